// Round 9
// baseline (51.176 us; speedup 1.0000x reference)
//
#include <hip/hip_runtime.h>
#include <hip/hip_bf16.h>
#include <stdint.h>

typedef unsigned short u16t;
typedef float f32x4 __attribute__((ext_vector_type(4)));
typedef short bf16x8 __attribute__((ext_vector_type(8)));

#define SDIM 224

__device__ __forceinline__ float lo16(uint32_t w) { union { uint32_t u; float f; } v; v.u = w << 16; return v.f; }
__device__ __forceinline__ float hi16(uint32_t w) { union { uint32_t u; float f; } v; v.u = w & 0xFFFF0000u; return v.f; }
__device__ __forceinline__ uint32_t f2bf(float f) {
    union { float f; uint32_t u; } v; v.f = f;
    return (v.u + 0x7FFFu + ((v.u >> 16) & 1u)) >> 16;
}

// ---------------------------------------------------------------------------
// Prep: pack all GEMM B-operands into MFMA-fragment order bf16.
// frag layout: buf[(kb*N + n)*8 + j] = bf16(W[kb*8+j][n])
// ---------------------------------------------------------------------------
__global__ void prep_wt_kernel(const float* __restrict__ h2wA, const float* __restrict__ h2wB,
                               const float* __restrict__ hb1w, const float* __restrict__ hw2w,
                               const float* __restrict__ hw1w,
                               u16t* __restrict__ wtA, u16t* __restrict__ wtB,
                               u16t* __restrict__ wt2, u16t* __restrict__ wtM)
{
    const int t0 = blockIdx.x * 256 + threadIdx.x, stride = gridDim.x * 256;
    for (int e = t0; e < 32768; e += stride) {
        int j = e & 7, n = (e >> 3) & 63, kb = e >> 9;
        int k = kb * 8 + j, h = k & 63, i = k >> 6;
        wtA[e] = (u16t)f2bf(h2wA[h * 512 + i * 64 + n]);
    }
    for (int e = t0; e < 24576; e += stride) {
        int j = e & 7, n = (e >> 3) & 63, kb = e >> 9;
        int k = kb * 8 + j, h = k & 63, i = k >> 6;
        wtB[e] = (u16t)f2bf(h2wB[h * 384 + i * 64 + n]);
    }
    for (int e = t0; e < 4096; e += stride) {
        int j = e & 7, n = (e >> 3) & 63, kb = e >> 9;
        int k = kb * 8 + j;
        float v = (n < 32) ? hb1w[k * 32 + n] : hw2w[k * 32 + (n - 32)];
        wt2[e] = (u16t)f2bf(v);
    }
    for (int e = t0; e < 2048; e += stride) {
        int j = e & 7, n = (e >> 3) & 31, kb = e >> 8;
        int k = kb * 8 + j;
        wtM[e] = (u16t)f2bf(hw1w[k * 32 + n]);
    }
}

// ---------------------------------------------------------------------------
// stage1: Psum[s][k=i*64+h] from bf16-staged x. lane = h, 4 samples/wave.
// ---------------------------------------------------------------------------
template<int DIN>
__device__ __forceinline__ void stage1_psum(const u16t (*s_xb)[SDIM], u16t* s_psum, int KP,
                                            const float* s_h1w, const float* s_h1b,
                                            float (*s_xsum)[8], int wave, int lane, int foff)
{
    float w1r[DIN];
#pragma unroll
    for (int i = 0; i < DIN; ++i) w1r[i] = s_h1w[i * 64 + lane];
    const float b1r = s_h1b[lane];
    for (int ss = 0; ss < 4; ++ss) {
        const int s = wave * 4 + ss;
        float ps[DIN], xs[DIN];
#pragma unroll
        for (int i = 0; i < DIN; ++i) { ps[i] = 0.f; xs[i] = 0.f; }
#pragma unroll
        for (int a = 0; a < 8; ++a) {
            float x[DIN];
            if constexpr (DIN == 8) {
                uint4 v = *(const uint4*)&s_xb[s][a * 8];
                x[0] = lo16(v.x); x[1] = hi16(v.x); x[2] = lo16(v.y); x[3] = hi16(v.y);
                x[4] = lo16(v.z); x[5] = hi16(v.z); x[6] = lo16(v.w); x[7] = hi16(v.w);
            } else {
                const u16t* p = &s_xb[s][foff + a * 6];
                uint32_t w0 = *(const uint32_t*)(p);
                uint32_t w1 = *(const uint32_t*)(p + 2);
                uint32_t w2 = *(const uint32_t*)(p + 4);
                x[0] = lo16(w0); x[1] = hi16(w0); x[2] = lo16(w1);
                x[3] = hi16(w1); x[4] = lo16(w2); x[5] = hi16(w2);
            }
            float hacc = b1r;
#pragma unroll
            for (int i = 0; i < DIN; ++i) hacc += x[i] * w1r[i];
            hacc = fmaxf(hacc, 0.f);
#pragma unroll
            for (int i = 0; i < DIN; ++i) { ps[i] += hacc * x[i]; xs[i] += x[i]; }
        }
#pragma unroll
        for (int i = 0; i < DIN; ++i) s_psum[s * KP + i * 64 + lane] = (u16t)f2bf(ps[i]);
        if (lane == 0) {
#pragma unroll
            for (int i = 0; i < DIN; ++i) s_xsum[s][i] = xs[i];
        }
    }
}

// ---------------------------------------------------------------------------
// Fully fused mixer: 16 samples/block, grid 1024, 256 threads, 4 blocks/CU.
// ---------------------------------------------------------------------------
__global__ __launch_bounds__(256, 4)
void fused_mixer(const float* __restrict__ qvals, const float* __restrict__ states,
                 const float* __restrict__ hs,
                 const float* __restrict__ al_h1w, const float* __restrict__ al_h1b,
                 const float* __restrict__ al_h2b, const float* __restrict__ al_bias,
                 const float* __restrict__ en_h1w, const float* __restrict__ en_h1b,
                 const float* __restrict__ en_h2b, const float* __restrict__ en_bias,
                 const float* __restrict__ act_w, const float* __restrict__ act_b,
                 const float* __restrict__ hb1_b, const float* __restrict__ hw2_b,
                 const float* __restrict__ hw1_b, const float* __restrict__ hb2_w,
                 const float* __restrict__ hb2_b,
                 const u16t* __restrict__ wtA, const u16t* __restrict__ wtB,
                 const u16t* __restrict__ wt2, const u16t* __restrict__ wtM,
                 float* __restrict__ out)
{
    __shared__ __align__(16) char  s_union[128 * 72 * 2];  // 18432 B: psum then hs
    __shared__ __align__(16) u16t  s_xb[16][SDIM];         // 7168 B (bf16 states)
    __shared__ __align__(16) u16t  s_se[16 * 72];          // 2304 B
    __shared__ float s_b1w2[16][64];                       // 4096 B
    __shared__ float s_b2[16];
    __shared__ float s_q[128];
    __shared__ float s_am[16][14];
    __shared__ float s_xsum[16][8];
    __shared__ float s_h1wA[512], s_h1wB[384];
    __shared__ float s_h1bA[64], s_h1bB[64], s_biasA[64], s_biasB[64], s_actb[64], s_hb2w[64];
    __shared__ float s_b1b[32], s_w2b[32], s_w1b[32];
    __shared__ float s_hb2b;

    const int tid  = threadIdx.x;
    const int wave = tid >> 6;
    const int lane = tid & 63;
    const int lr = lane & 15, lg = lane >> 4;
    const int sbase = blockIdx.x * 16;
    const int o = wave * 16 + lr;                          // this thread's output column

    // ---- early issue: hs -> regs (T14), per-lane weight columns -> regs ----
    float4 hsr[8];
    {
        const float4* hsv = (const float4*)(hs + (size_t)sbase * 512);
#pragma unroll
        for (int i = 0; i < 8; ++i) hsr[i] = hsv[i * 256 + tid];
    }
    float h2bA_r[8], h2bB_r[6], actw_r[14];
#pragma unroll
    for (int i = 0; i < 8; ++i) h2bA_r[i] = al_h2b[i * 64 + o];
#pragma unroll
    for (int i = 0; i < 6; ++i) h2bB_r[i] = en_h2b[i * 64 + o];
#pragma unroll
    for (int j = 0; j < 14; ++j) actw_r[j] = act_w[j * 64 + o];
    if (tid < 128) s_q[tid] = qvals[(size_t)sbase * 8 + tid];

    // ---- cooperative staging ----
    for (int i = tid; i < 16 * 28; i += 256) {             // states f32 -> bf16 LDS
        int s = i / 28, c = i - s * 28;
        const float4* sp = (const float4*)(states + (size_t)(sbase + s) * SDIM + c * 8);
        float4 v0 = sp[0], v1 = sp[1];
        uint4 p;
        p.x = f2bf(v0.x) | (f2bf(v0.y) << 16);
        p.y = f2bf(v0.z) | (f2bf(v0.w) << 16);
        p.z = f2bf(v1.x) | (f2bf(v1.y) << 16);
        p.w = f2bf(v1.z) | (f2bf(v1.w) << 16);
        *(uint4*)&s_xb[s][c * 8] = p;
    }
    for (int i = tid; i < 512; i += 256) s_h1wA[i] = al_h1w[i];
    for (int i = tid; i < 384; i += 256) s_h1wB[i] = en_h1w[i];
    if (tid < 64) {
        s_h1bA[tid] = al_h1b[tid]; s_h1bB[tid] = en_h1b[tid];
        s_biasA[tid] = al_bias[tid]; s_biasB[tid] = en_bias[tid];
        s_actb[tid] = act_b[tid]; s_hb2w[tid] = hb2_w[tid];
    }
    if (tid >= 64 && tid < 96)  s_b1b[tid - 64] = hb1_b[tid - 64];
    if (tid >= 96 && tid < 128) s_w2b[tid - 96] = hw2_b[tid - 96];
    if (tid >= 128 && tid < 160) s_w1b[tid - 128] = hw1_b[tid - 128];
    if (tid == 160) s_hb2b = hb2_b[0];
    __syncthreads();                                   // B0

    u16t* s_psum = (u16t*)s_union;
    constexpr int KPA = 520, KPB = 392;

    // ---- phase A stage1 + action means ----
    stage1_psum<8>(s_xb, s_psum, KPA, s_h1wA, s_h1bA, s_xsum, wave, lane, 0);
    for (int i = tid; i < 224; i += 256) {
        int s = i / 14, j = i - s * 14;
        float a = 0.f;
#pragma unroll
        for (int aa = 0; aa < 8; ++aa) a += lo16((uint32_t)s_xb[s][112 + aa * 14 + j]);
        s_am[s][j] = a * 0.125f;
    }
    __syncthreads();                                   // B1

    // ---- phase A MFMA (M=16, N=64 split across waves, K=512) ----
    float e[4];
    {
        f32x4 acc = {0.f, 0.f, 0.f, 0.f};
        const u16t* arow = &s_psum[lr * KPA + lg * 8];
        const bf16x8* wt8 = (const bf16x8*)wtA;
#pragma unroll 4
        for (int kk = 0; kk < 512; kk += 32) {
            bf16x8 av = *(const bf16x8*)(arow + kk);
            bf16x8 bv = wt8[((kk >> 3) + lg) * 64 + o];
            acc = __builtin_amdgcn_mfma_f32_16x16x32_bf16(av, bv, acc, 0, 0, 0);
        }
#pragma unroll
        for (int j = 0; j < 4; ++j) {
            const int row = lg * 4 + j;
            float hb = 0.f;
#pragma unroll
            for (int i = 0; i < 8; ++i) hb += s_xsum[row][i] * h2bA_r[i];
            e[j] = (acc[j] + hb) * 0.125f + s_biasA[o];
        }
    }
    __syncthreads();                                   // B2 (psum free)

    // ---- phase B stage1 ----
    stage1_psum<6>(s_xb, s_psum, KPB, s_h1wB, s_h1bB, s_xsum, wave, lane, 64);
    __syncthreads();                                   // B3

    // ---- phase B MFMA + se epilogue ----
    {
        f32x4 acc = {0.f, 0.f, 0.f, 0.f};
        const u16t* arow = &s_psum[lr * KPB + lg * 8];
        const bf16x8* wt8 = (const bf16x8*)wtB;
#pragma unroll 4
        for (int kk = 0; kk < 384; kk += 32) {
            bf16x8 av = *(const bf16x8*)(arow + kk);
            bf16x8 bv = wt8[((kk >> 3) + lg) * 64 + o];
            acc = __builtin_amdgcn_mfma_f32_16x16x32_bf16(av, bv, acc, 0, 0, 0);
        }
#pragma unroll
        for (int j = 0; j < 4; ++j) {
            const int row = lg * 4 + j;
            float hb = 0.f;
#pragma unroll
            for (int i = 0; i < 6; ++i) hb += s_xsum[row][i] * h2bB_r[i];
            float se = e[j] + (acc[j] + hb) * 0.125f + s_biasB[o] + s_actb[o];
#pragma unroll
            for (int j2 = 0; j2 < 14; ++j2) se += s_am[row][j2] * actw_r[j2];
            se = fmaxf(se, 0.f);
            s_se[row * 72 + o] = (u16t)f2bf(se);
        }
    }
    __syncthreads();                                   // B4 (se ready, psum free)

    // ---- region: hs regs -> LDS | b1w2 MFMA | b2 reduce ----
    u16t* s_hs = (u16t*)s_union;
    {
#pragma unroll
        for (int i = 0; i < 8; ++i) {
            const int idx = i * 256 + tid;
            const int row = idx >> 4, c4 = idx & 15;
            uint2 p;
            p.x = f2bf(hsr[i].x) | (f2bf(hsr[i].y) << 16);
            p.y = f2bf(hsr[i].z) | (f2bf(hsr[i].w) << 16);
            *(uint2*)&s_hs[row * 72 + c4 * 4] = p;
        }
    }
    {   // b1w2: M=16 samples, K=64 se, N=64 (b1|w2)
        f32x4 acc = {0.f, 0.f, 0.f, 0.f};
        const bf16x8* wt8 = (const bf16x8*)wt2;
#pragma unroll
        for (int ks = 0; ks < 2; ++ks) {
            bf16x8 av = *(const bf16x8*)&s_se[lr * 72 + ks * 32 + lg * 8];
            bf16x8 bv = wt8[(ks * 4 + lg) * 64 + o];
            acc = __builtin_amdgcn_mfma_f32_16x16x32_bf16(av, bv, acc, 0, 0, 0);
        }
#pragma unroll
        for (int j = 0; j < 4; ++j) {
            const int row = lg * 4 + j;
            float v = acc[j] + ((o < 32) ? s_b1b[o] : s_w2b[o - 32]);
            if (o >= 32) v = fabsf(v);
            s_b1w2[row][o] = v;
        }
    }
    {   // b2: wave handles 4 samples, 16-lane groups reduce over o
        const int smp = wave * 4 + lg;
        float p = 0.f;
#pragma unroll
        for (int c = 0; c < 4; ++c) {
            const int oo = c * 16 + lr;
            p += lo16((uint32_t)s_se[smp * 72 + oo]) * s_hb2w[oo];
        }
        p += __shfl_xor(p, 1); p += __shfl_xor(p, 2);
        p += __shfl_xor(p, 4); p += __shfl_xor(p, 8);
        if (lr == 0) s_b2[smp] = p + s_hb2b;
    }
    __syncthreads();                                   // B5

    // ---- mix: z MFMA, softmax over 8 agents, q-mix, ELU, dot w2 ----
    bf16x8 bfr[2][2];
    {
        const bf16x8* wtm8 = (const bf16x8*)wtM;
#pragma unroll
        for (int n = 0; n < 2; ++n)
#pragma unroll
            for (int ks = 0; ks < 2; ++ks)
                bfr[n][ks] = wtm8[(ks * 4 + lg) * 32 + n * 16 + lr];
    }
    const float zb0 = s_w1b[lr], zb1 = s_w1b[16 + lr];

    for (int t = wave * 2; t < wave * 2 + 2; ++t) {
        f32x4 d0 = {0.f, 0.f, 0.f, 0.f}, d1 = {0.f, 0.f, 0.f, 0.f};
#pragma unroll
        for (int ks = 0; ks < 2; ++ks) {
            bf16x8 av = *(const bf16x8*)&s_hs[(t * 16 + lr) * 72 + ks * 32 + lg * 8];
            d0 = __builtin_amdgcn_mfma_f32_16x16x32_bf16(av, bfr[0][ks], d0, 0, 0, 0);
            d1 = __builtin_amdgcn_mfma_f32_16x16x32_bf16(av, bfr[1][ks], d1, 0, 0, 0);
        }
        const int sloc = t * 2 + (lg >> 1);
        float z0[4], z1[4];
#pragma unroll
        for (int j = 0; j < 4; ++j) { z0[j] = d0[j] + zb0; z1[j] = d1[j] + zb1; }
        float m0 = fmaxf(fmaxf(z0[0], z0[1]), fmaxf(z0[2], z0[3]));
        float m1 = fmaxf(fmaxf(z1[0], z1[1]), fmaxf(z1[2], z1[3]));
        m0 = fmaxf(m0, __shfl_xor(m0, 16));
        m1 = fmaxf(m1, __shfl_xor(m1, 16));
        float qa[4];
        {
            float4 qv = *(const float4*)&s_q[sloc * 8 + (lg & 1) * 4];
            qa[0] = qv.x; qa[1] = qv.y; qa[2] = qv.z; qa[3] = qv.w;
        }
        float s0 = 0.f, s1 = 0.f, hp0 = 0.f, hp1 = 0.f;
#pragma unroll
        for (int j = 0; j < 4; ++j) {
            float e0 = __expf(z0[j] - m0), e1 = __expf(z1[j] - m1);
            s0 += e0; s1 += e1;
            hp0 += qa[j] * e0; hp1 += qa[j] * e1;
        }
        s0  += __shfl_xor(s0, 16);  s1  += __shfl_xor(s1, 16);
        hp0 += __shfl_xor(hp0, 16); hp1 += __shfl_xor(hp1, 16);

        const float b1_0 = s_b1w2[sloc][lr],      b1_1 = s_b1w2[sloc][16 + lr];
        const float w2_0 = s_b1w2[sloc][32 + lr], w2_1 = s_b1w2[sloc][48 + lr];
        float h0 = hp0 / s0 + b1_0; h0 = (h0 > 0.f) ? h0 : (__expf(h0) - 1.f);
        float h1 = hp1 / s1 + b1_1; h1 = (h1 > 0.f) ? h1 : (__expf(h1) - 1.f);
        float yp = h0 * w2_0 + h1 * w2_1;
        yp += __shfl_xor(yp, 1); yp += __shfl_xor(yp, 2);
        yp += __shfl_xor(yp, 4); yp += __shfl_xor(yp, 8);
        if (lr == 0 && (lg & 1) == 0) out[sbase + sloc] = yp + s_b2[sloc];
    }
}

extern "C" void kernel_launch(void* const* d_in, const int* in_sizes, int n_in,
                              void* d_out, int out_size, void* d_ws, size_t ws_size,
                              hipStream_t stream) {
    const float* qvals   = (const float*)d_in[0];
    const float* states  = (const float*)d_in[1];
    const float* hstates = (const float*)d_in[2];
    const float* hw1_w   = (const float*)d_in[3];
    const float* hw1_b   = (const float*)d_in[4];
    const float* en_h1w  = (const float*)d_in[5];
    const float* en_h1b  = (const float*)d_in[6];
    const float* en_h2w  = (const float*)d_in[7];
    const float* en_h2b  = (const float*)d_in[8];
    const float* en_bias = (const float*)d_in[9];
    const float* al_h1w  = (const float*)d_in[10];
    const float* al_h1b  = (const float*)d_in[11];
    const float* al_h2w  = (const float*)d_in[12];
    const float* al_h2b  = (const float*)d_in[13];
    const float* al_bias = (const float*)d_in[14];
    const float* act_w   = (const float*)d_in[15];
    const float* act_b   = (const float*)d_in[16];
    const float* hb1_w   = (const float*)d_in[17];
    const float* hb1_b   = (const float*)d_in[18];
    const float* hw2_w   = (const float*)d_in[19];
    const float* hw2_b   = (const float*)d_in[20];
    const float* hb2_w   = (const float*)d_in[21];
    const float* hb2_b   = (const float*)d_in[22];

    // ws (u16 units): wtA@0 (32768) | wtB@32768 (24576) | wt2@57344 (4096) | wtM@61440 (2048)
    u16t* wtA = (u16t*)d_ws;
    u16t* wtB = wtA + 32768;
    u16t* wt2 = wtA + 57344;
    u16t* wtM = wtA + 61440;

    prep_wt_kernel<<<64, 256, 0, stream>>>(al_h2w, en_h2w, hb1_w, hw2_w, hw1_w, wtA, wtB, wt2, wtM);
    fused_mixer<<<1024, 256, 0, stream>>>(qvals, states, hstates,
                                          al_h1w, al_h1b, al_h2b, al_bias,
                                          en_h1w, en_h1b, en_h2b, en_bias,
                                          act_w, act_b, hb1_b, hw2_b, hw1_b, hb2_w, hb2_b,
                                          wtA, wtB, wt2, wtM, (float*)d_out);
}

// Round 10
// 34.872 us; speedup vs baseline: 1.4675x; 1.4675x over previous
//
#include <hip/hip_runtime.h>
#include <hip/hip_bf16.h>
#include <stdint.h>

typedef unsigned short u16t;
typedef float f32x4 __attribute__((ext_vector_type(4)));
typedef short bf16x8 __attribute__((ext_vector_type(8)));

#define SDIM 224

__device__ __forceinline__ float lo16(uint32_t w) { union { uint32_t u; float f; } v; v.u = w << 16; return v.f; }
__device__ __forceinline__ float hi16(uint32_t w) { union { uint32_t u; float f; } v; v.u = w & 0xFFFF0000u; return v.f; }
__device__ __forceinline__ uint32_t f2bf(float f) {
    union { float f; uint32_t u; } v; v.f = f;
    return (v.u + 0x7FFFu + ((v.u >> 16) & 1u)) >> 16;
}

// ---------------------------------------------------------------------------
// Prep: pack all GEMM B-operands into MFMA-fragment order bf16.
// frag layout: buf[(kb*N + n)*8 + j] = bf16(W[kb*8+j][n])
// ---------------------------------------------------------------------------
__global__ void prep_wt_kernel(const float* __restrict__ h2wA, const float* __restrict__ h2wB,
                               const float* __restrict__ hb1w, const float* __restrict__ hw2w,
                               const float* __restrict__ hw1w,
                               u16t* __restrict__ wtA, u16t* __restrict__ wtB,
                               u16t* __restrict__ wt2, u16t* __restrict__ wtM)
{
    const int t0 = blockIdx.x * 256 + threadIdx.x, stride = gridDim.x * 256;
    for (int e = t0; e < 32768; e += stride) {
        int j = e & 7, n = (e >> 3) & 63, kb = e >> 9;
        int k = kb * 8 + j, h = k & 63, i = k >> 6;
        wtA[e] = (u16t)f2bf(h2wA[h * 512 + i * 64 + n]);
    }
    for (int e = t0; e < 24576; e += stride) {
        int j = e & 7, n = (e >> 3) & 63, kb = e >> 9;
        int k = kb * 8 + j, h = k & 63, i = k >> 6;
        wtB[e] = (u16t)f2bf(h2wB[h * 384 + i * 64 + n]);
    }
    for (int e = t0; e < 4096; e += stride) {
        int j = e & 7, n = (e >> 3) & 63, kb = e >> 9;
        int k = kb * 8 + j;
        float v = (n < 32) ? hb1w[k * 32 + n] : hw2w[k * 32 + (n - 32)];
        wt2[e] = (u16t)f2bf(v);
    }
    for (int e = t0; e < 2048; e += stride) {
        int j = e & 7, n = (e >> 3) & 31, kb = e >> 8;
        int k = kb * 8 + j;
        wtM[e] = (u16t)f2bf(hw1w[k * 32 + n]);
    }
}

// ---------------------------------------------------------------------------
// stage1: Psum[s][k=i*64+h] from bf16-staged x. lane = h, 4 samples/wave.
// ---------------------------------------------------------------------------
template<int DIN>
__device__ __forceinline__ void stage1_psum(const u16t (*s_xb)[SDIM], u16t* s_psum, int KP,
                                            const float* s_h1w, const float* s_h1b,
                                            float (*s_xsum)[8], int wave, int lane, int foff)
{
    float w1r[DIN];
#pragma unroll
    for (int i = 0; i < DIN; ++i) w1r[i] = s_h1w[i * 64 + lane];
    const float b1r = s_h1b[lane];
    for (int ss = 0; ss < 4; ++ss) {
        const int s = wave * 4 + ss;
        float ps[DIN], xs[DIN];
#pragma unroll
        for (int i = 0; i < DIN; ++i) { ps[i] = 0.f; xs[i] = 0.f; }
#pragma unroll
        for (int a = 0; a < 8; ++a) {
            float x[DIN];
            if constexpr (DIN == 8) {
                uint4 v = *(const uint4*)&s_xb[s][a * 8];
                x[0] = lo16(v.x); x[1] = hi16(v.x); x[2] = lo16(v.y); x[3] = hi16(v.y);
                x[4] = lo16(v.z); x[5] = hi16(v.z); x[6] = lo16(v.w); x[7] = hi16(v.w);
            } else {
                const u16t* p = &s_xb[s][foff + a * 6];
                uint32_t w0 = *(const uint32_t*)(p);
                uint32_t w1 = *(const uint32_t*)(p + 2);
                uint32_t w2 = *(const uint32_t*)(p + 4);
                x[0] = lo16(w0); x[1] = hi16(w0); x[2] = lo16(w1);
                x[3] = hi16(w1); x[4] = lo16(w2); x[5] = hi16(w2);
            }
            float hacc = b1r;
#pragma unroll
            for (int i = 0; i < DIN; ++i) hacc += x[i] * w1r[i];
            hacc = fmaxf(hacc, 0.f);
#pragma unroll
            for (int i = 0; i < DIN; ++i) { ps[i] += hacc * x[i]; xs[i] += x[i]; }
        }
#pragma unroll
        for (int i = 0; i < DIN; ++i) s_psum[s * KP + i * 64 + lane] = (u16t)f2bf(ps[i]);
        if (lane == 0) {
#pragma unroll
            for (int i = 0; i < DIN; ++i) s_xsum[s][i] = xs[i];
        }
    }
}

// ---------------------------------------------------------------------------
// Fully fused mixer: 16 samples/block, grid 1024, 256 threads, 4 blocks/CU.
// All heavy register payloads are loaded within one barrier-phase of their
// use (R9 lesson: long-lived regs + launch_bounds(,4) => scratch spills).
// ---------------------------------------------------------------------------
__global__ __launch_bounds__(256, 4)
void fused_mixer(const float* __restrict__ qvals, const float* __restrict__ states,
                 const float* __restrict__ hs,
                 const float* __restrict__ al_h1w, const float* __restrict__ al_h1b,
                 const float* __restrict__ al_h2b, const float* __restrict__ al_bias,
                 const float* __restrict__ en_h1w, const float* __restrict__ en_h1b,
                 const float* __restrict__ en_h2b, const float* __restrict__ en_bias,
                 const float* __restrict__ act_w, const float* __restrict__ act_b,
                 const float* __restrict__ hb1_b, const float* __restrict__ hw2_b,
                 const float* __restrict__ hw1_b, const float* __restrict__ hb2_w,
                 const float* __restrict__ hb2_b,
                 const u16t* __restrict__ wtA, const u16t* __restrict__ wtB,
                 const u16t* __restrict__ wt2, const u16t* __restrict__ wtM,
                 float* __restrict__ out)
{
    __shared__ __align__(16) char  s_union[128 * 72 * 2];  // 18432 B: psum then hs
    __shared__ __align__(16) u16t  s_xb[16][SDIM];         // 7168 B (bf16 states)
    __shared__ __align__(16) u16t  s_se[16 * 72];          // 2304 B
    __shared__ float s_b1w2[16][64];                       // 4096 B
    __shared__ float s_b2[16];
    __shared__ float s_q[128];
    __shared__ float s_am[16][14];
    __shared__ float s_xsum[16][8];
    __shared__ float s_h1wA[512], s_h1wB[384];
    __shared__ float s_h1bA[64], s_h1bB[64], s_biasA[64], s_biasB[64], s_actb[64], s_hb2w[64];
    __shared__ float s_b1b[32], s_w2b[32], s_w1b[32];
    __shared__ float s_hb2b;

    const int tid  = threadIdx.x;
    const int wave = tid >> 6;
    const int lane = tid & 63;
    const int lr = lane & 15, lg = lane >> 4;
    const int sbase = blockIdx.x * 16;
    const int o = wave * 16 + lr;                          // this thread's output column

    if (tid < 128) s_q[tid] = qvals[(size_t)sbase * 8 + tid];

    // ---- cooperative staging ----
    for (int i = tid; i < 16 * 28; i += 256) {             // states f32 -> bf16 LDS
        int s = i / 28, c = i - s * 28;
        const float4* sp = (const float4*)(states + (size_t)(sbase + s) * SDIM + c * 8);
        float4 v0 = sp[0], v1 = sp[1];
        uint4 p;
        p.x = f2bf(v0.x) | (f2bf(v0.y) << 16);
        p.y = f2bf(v0.z) | (f2bf(v0.w) << 16);
        p.z = f2bf(v1.x) | (f2bf(v1.y) << 16);
        p.w = f2bf(v1.z) | (f2bf(v1.w) << 16);
        *(uint4*)&s_xb[s][c * 8] = p;
    }
    for (int i = tid; i < 512; i += 256) s_h1wA[i] = al_h1w[i];
    for (int i = tid; i < 384; i += 256) s_h1wB[i] = en_h1w[i];
    if (tid < 64) {
        s_h1bA[tid] = al_h1b[tid]; s_h1bB[tid] = en_h1b[tid];
        s_biasA[tid] = al_bias[tid]; s_biasB[tid] = en_bias[tid];
        s_actb[tid] = act_b[tid]; s_hb2w[tid] = hb2_w[tid];
    }
    if (tid >= 64 && tid < 96)  s_b1b[tid - 64] = hb1_b[tid - 64];
    if (tid >= 96 && tid < 128) s_w2b[tid - 96] = hw2_b[tid - 96];
    if (tid >= 128 && tid < 160) s_w1b[tid - 128] = hw1_b[tid - 128];
    if (tid == 160) s_hb2b = hb2_b[0];
    __syncthreads();                                   // B0

    u16t* s_psum = (u16t*)s_union;
    constexpr int KPA = 520, KPB = 392;

    // ---- phase A stage1 + action means ----
    stage1_psum<8>(s_xb, s_psum, KPA, s_h1wA, s_h1bA, s_xsum, wave, lane, 0);
    for (int i = tid; i < 224; i += 256) {
        int s = i / 14, j = i - s * 14;
        float a = 0.f;
#pragma unroll
        for (int aa = 0; aa < 8; ++aa) a += lo16((uint32_t)s_xb[s][112 + aa * 14 + j]);
        s_am[s][j] = a * 0.125f;
    }
    __syncthreads();                                   // B1

    // ---- phase A MFMA (M=16, N=64 split across waves, K=512) ----
    float e[4];
    {
        float h2bA_r[8];                               // issued here, used in epilogue
#pragma unroll
        for (int i = 0; i < 8; ++i) h2bA_r[i] = al_h2b[i * 64 + o];
        f32x4 acc = {0.f, 0.f, 0.f, 0.f};
        const u16t* arow = &s_psum[lr * KPA + lg * 8];
        const bf16x8* wt8 = (const bf16x8*)wtA;
#pragma unroll 4
        for (int kk = 0; kk < 512; kk += 32) {
            bf16x8 av = *(const bf16x8*)(arow + kk);
            bf16x8 bv = wt8[((kk >> 3) + lg) * 64 + o];
            acc = __builtin_amdgcn_mfma_f32_16x16x32_bf16(av, bv, acc, 0, 0, 0);
        }
#pragma unroll
        for (int j = 0; j < 4; ++j) {
            const int row = lg * 4 + j;
            float hb = 0.f;
#pragma unroll
            for (int i = 0; i < 8; ++i) hb += s_xsum[row][i] * h2bA_r[i];
            e[j] = (acc[j] + hb) * 0.125f + s_biasA[o];
        }
    }
    __syncthreads();                                   // B2 (psum free)

    // ---- phase B stage1 ----
    stage1_psum<6>(s_xb, s_psum, KPB, s_h1wB, s_h1bB, s_xsum, wave, lane, 64);
    __syncthreads();                                   // B3

    // ---- phase B: issue hs + weight loads, MFMA, se epilogue ----
    float4 hsr[8];
    {
        const float4* hsv = (const float4*)(hs + (size_t)sbase * 512);
#pragma unroll
        for (int i = 0; i < 8; ++i) hsr[i] = hsv[i * 256 + tid];
    }
    {
        float h2bB_r[6], actw_r[14];
#pragma unroll
        for (int i = 0; i < 6; ++i) h2bB_r[i] = en_h2b[i * 64 + o];
#pragma unroll
        for (int j = 0; j < 14; ++j) actw_r[j] = act_w[j * 64 + o];

        f32x4 acc = {0.f, 0.f, 0.f, 0.f};
        const u16t* arow = &s_psum[lr * KPB + lg * 8];
        const bf16x8* wt8 = (const bf16x8*)wtB;
#pragma unroll 4
        for (int kk = 0; kk < 384; kk += 32) {
            bf16x8 av = *(const bf16x8*)(arow + kk);
            bf16x8 bv = wt8[((kk >> 3) + lg) * 64 + o];
            acc = __builtin_amdgcn_mfma_f32_16x16x32_bf16(av, bv, acc, 0, 0, 0);
        }
#pragma unroll
        for (int j = 0; j < 4; ++j) {
            const int row = lg * 4 + j;
            float hb = 0.f;
#pragma unroll
            for (int i = 0; i < 6; ++i) hb += s_xsum[row][i] * h2bB_r[i];
            float se = e[j] + (acc[j] + hb) * 0.125f + s_biasB[o] + s_actb[o];
#pragma unroll
            for (int j2 = 0; j2 < 14; ++j2) se += s_am[row][j2] * actw_r[j2];
            se = fmaxf(se, 0.f);
            s_se[row * 72 + o] = (u16t)f2bf(se);
        }
    }
    __syncthreads();                                   // B4 (se ready, psum free)

    // ---- region: hs regs -> LDS | b1w2 MFMA | b2 reduce ----
    u16t* s_hs = (u16t*)s_union;
    {
#pragma unroll
        for (int i = 0; i < 8; ++i) {
            const int idx = i * 256 + tid;
            const int row = idx >> 4, c4 = idx & 15;
            uint2 p;
            p.x = f2bf(hsr[i].x) | (f2bf(hsr[i].y) << 16);
            p.y = f2bf(hsr[i].z) | (f2bf(hsr[i].w) << 16);
            *(uint2*)&s_hs[row * 72 + c4 * 4] = p;
        }
    }
    {   // b1w2: M=16 samples, K=64 se, N=64 (b1|w2)
        f32x4 acc = {0.f, 0.f, 0.f, 0.f};
        const bf16x8* wt8 = (const bf16x8*)wt2;
#pragma unroll
        for (int ks = 0; ks < 2; ++ks) {
            bf16x8 av = *(const bf16x8*)&s_se[lr * 72 + ks * 32 + lg * 8];
            bf16x8 bv = wt8[(ks * 4 + lg) * 64 + o];
            acc = __builtin_amdgcn_mfma_f32_16x16x32_bf16(av, bv, acc, 0, 0, 0);
        }
#pragma unroll
        for (int j = 0; j < 4; ++j) {
            const int row = lg * 4 + j;
            float v = acc[j] + ((o < 32) ? s_b1b[o] : s_w2b[o - 32]);
            if (o >= 32) v = fabsf(v);
            s_b1w2[row][o] = v;
        }
    }
    {   // b2: wave handles 4 samples, 16-lane groups reduce over o
        const int smp = wave * 4 + lg;
        float p = 0.f;
#pragma unroll
        for (int c = 0; c < 4; ++c) {
            const int oo = c * 16 + lr;
            p += lo16((uint32_t)s_se[smp * 72 + oo]) * s_hb2w[oo];
        }
        p += __shfl_xor(p, 1); p += __shfl_xor(p, 2);
        p += __shfl_xor(p, 4); p += __shfl_xor(p, 8);
        if (lr == 0) s_b2[smp] = p + s_hb2b;
    }
    __syncthreads();                                   // B5

    // ---- mix: z MFMA, softmax over 8 agents, q-mix, ELU, dot w2 ----
    bf16x8 bfr[2][2];
    {
        const bf16x8* wtm8 = (const bf16x8*)wtM;
#pragma unroll
        for (int n = 0; n < 2; ++n)
#pragma unroll
            for (int ks = 0; ks < 2; ++ks)
                bfr[n][ks] = wtm8[(ks * 4 + lg) * 32 + n * 16 + lr];
    }
    const float zb0 = s_w1b[lr], zb1 = s_w1b[16 + lr];

    for (int t = wave * 2; t < wave * 2 + 2; ++t) {
        f32x4 d0 = {0.f, 0.f, 0.f, 0.f}, d1 = {0.f, 0.f, 0.f, 0.f};
#pragma unroll
        for (int ks = 0; ks < 2; ++ks) {
            bf16x8 av = *(const bf16x8*)&s_hs[(t * 16 + lr) * 72 + ks * 32 + lg * 8];
            d0 = __builtin_amdgcn_mfma_f32_16x16x32_bf16(av, bfr[0][ks], d0, 0, 0, 0);
            d1 = __builtin_amdgcn_mfma_f32_16x16x32_bf16(av, bfr[1][ks], d1, 0, 0, 0);
        }
        const int sloc = t * 2 + (lg >> 1);
        float z0[4], z1[4];
#pragma unroll
        for (int j = 0; j < 4; ++j) { z0[j] = d0[j] + zb0; z1[j] = d1[j] + zb1; }
        float m0 = fmaxf(fmaxf(z0[0], z0[1]), fmaxf(z0[2], z0[3]));
        float m1 = fmaxf(fmaxf(z1[0], z1[1]), fmaxf(z1[2], z1[3]));
        m0 = fmaxf(m0, __shfl_xor(m0, 16));
        m1 = fmaxf(m1, __shfl_xor(m1, 16));
        float qa[4];
        {
            float4 qv = *(const float4*)&s_q[sloc * 8 + (lg & 1) * 4];
            qa[0] = qv.x; qa[1] = qv.y; qa[2] = qv.z; qa[3] = qv.w;
        }
        float s0 = 0.f, s1 = 0.f, hp0 = 0.f, hp1 = 0.f;
#pragma unroll
        for (int j = 0; j < 4; ++j) {
            float e0 = __expf(z0[j] - m0), e1 = __expf(z1[j] - m1);
            s0 += e0; s1 += e1;
            hp0 += qa[j] * e0; hp1 += qa[j] * e1;
        }
        s0  += __shfl_xor(s0, 16);  s1  += __shfl_xor(s1, 16);
        hp0 += __shfl_xor(hp0, 16); hp1 += __shfl_xor(hp1, 16);

        const float b1_0 = s_b1w2[sloc][lr],      b1_1 = s_b1w2[sloc][16 + lr];
        const float w2_0 = s_b1w2[sloc][32 + lr], w2_1 = s_b1w2[sloc][48 + lr];
        float h0 = hp0 / s0 + b1_0; h0 = (h0 > 0.f) ? h0 : (__expf(h0) - 1.f);
        float h1 = hp1 / s1 + b1_1; h1 = (h1 > 0.f) ? h1 : (__expf(h1) - 1.f);
        float yp = h0 * w2_0 + h1 * w2_1;
        yp += __shfl_xor(yp, 1); yp += __shfl_xor(yp, 2);
        yp += __shfl_xor(yp, 4); yp += __shfl_xor(yp, 8);
        if (lr == 0 && (lg & 1) == 0) out[sbase + sloc] = yp + s_b2[sloc];
    }
}

extern "C" void kernel_launch(void* const* d_in, const int* in_sizes, int n_in,
                              void* d_out, int out_size, void* d_ws, size_t ws_size,
                              hipStream_t stream) {
    const float* qvals   = (const float*)d_in[0];
    const float* states  = (const float*)d_in[1];
    const float* hstates = (const float*)d_in[2];
    const float* hw1_w   = (const float*)d_in[3];
    const float* hw1_b   = (const float*)d_in[4];
    const float* en_h1w  = (const float*)d_in[5];
    const float* en_h1b  = (const float*)d_in[6];
    const float* en_h2w  = (const float*)d_in[7];
    const float* en_h2b  = (const float*)d_in[8];
    const float* en_bias = (const float*)d_in[9];
    const float* al_h1w  = (const float*)d_in[10];
    const float* al_h1b  = (const float*)d_in[11];
    const float* al_h2w  = (const float*)d_in[12];
    const float* al_h2b  = (const float*)d_in[13];
    const float* al_bias = (const float*)d_in[14];
    const float* act_w   = (const float*)d_in[15];
    const float* act_b   = (const float*)d_in[16];
    const float* hb1_w   = (const float*)d_in[17];
    const float* hb1_b   = (const float*)d_in[18];
    const float* hw2_w   = (const float*)d_in[19];
    const float* hw2_b   = (const float*)d_in[20];
    const float* hb2_w   = (const float*)d_in[21];
    const float* hb2_b   = (const float*)d_in[22];

    // ws (u16 units): wtA@0 (32768) | wtB@32768 (24576) | wt2@57344 (4096) | wtM@61440 (2048)
    u16t* wtA = (u16t*)d_ws;
    u16t* wtB = wtA + 32768;
    u16t* wt2 = wtA + 57344;
    u16t* wtM = wtA + 61440;

    prep_wt_kernel<<<64, 256, 0, stream>>>(al_h2w, en_h2w, hb1_w, hw2_w, hw1_w, wtA, wtB, wt2, wtM);
    fused_mixer<<<1024, 256, 0, stream>>>(qvals, states, hstates,
                                          al_h1w, al_h1b, al_h2b, al_bias,
                                          en_h1w, en_h1b, en_h2b, en_bias,
                                          act_w, act_b, hb1_b, hw2_b, hw1_b, hb2_w, hb2_b,
                                          wtA, wtB, wt2, wtM, (float*)d_out);
}